// Round 19
// baseline (108.666 us; speedup 1.0000x reference)
//
#include <hip/hip_runtime.h>
#include <hip/hip_bf16.h>
#include <stdint.h>

typedef __bf16 bf16x8 __attribute__((ext_vector_type(8)));
typedef float  f32x4  __attribute__((ext_vector_type(4)));
typedef unsigned short u16x8 __attribute__((ext_vector_type(8)));
typedef unsigned int   u32x4 __attribute__((ext_vector_type(4)));

#define LOG2E 1.4426950408889634f

__device__ __forceinline__ unsigned short f2bf(float f) {
    union { float f; unsigned u; } v; v.f = f;
    unsigned r = v.u + 0x7fffu + ((v.u >> 16) & 1u);   // RNE
    return (unsigned short)(r >> 16);
}
__device__ __forceinline__ float lo16(unsigned d) {
    union { unsigned u; float f; } v; v.u = d << 16; return v.f;
}
__device__ __forceinline__ float hi16(unsigned d) {
    union { unsigned u; float f; } v; v.u = d & 0xffff0000u; return v.f;
}
__device__ __forceinline__ float fexp2(float x) {
    float r; asm("v_exp_f32 %0, %1" : "=v"(r) : "v"(x)); return r;
}
__device__ __forceinline__ float frcp(float x) {
    float r; asm("v_rcp_f32 %0, %1" : "=v"(r) : "v"(x)); return r;
}

__device__ __forceinline__ void async16(void* lds, const void* g) {
    __builtin_amdgcn_global_load_lds(
        (const __attribute__((address_space(1))) unsigned int*)g,
        (__attribute__((address_space(3))) unsigned int*)lds, 16, 0, 0);
}

#define NT_ALL   21504
#define OFF_L1   16384
#define OFF_L2   20480

// ---------------- fused prep: feat=0 | w fp32->bf16 (x8 vec) | x -> xT ------
__global__ __launch_bounds__(256) void prep_kernel(
    const float* __restrict__ x0, const float* __restrict__ x1,
    const float* __restrict__ x2,
    const float* __restrict__ wq, const float* __restrict__ wk,
    const float* __restrict__ wv,
    unsigned short* __restrict__ wb, unsigned short* __restrict__ xT,
    float* __restrict__ feat)
{
    __shared__ unsigned short tile[64][65];
    int bid = blockIdx.x;
    if (bid == 0) {
        for (int i = threadIdx.x; i < 2048; i += 256) feat[i] = 0.f;
        return;
    }
    bid -= 1;
    if (bid < 576) {                         // weight convert, 8 elems/thread
        int t = bid / 192;
        int i = ((bid % 192) * 256 + threadIdx.x) * 8;
        const float* src = (t == 0) ? wq : (t == 1) ? wk : wv;
        f32x4 a = *(const f32x4*)(src + i);
        f32x4 b = *(const f32x4*)(src + i + 4);
        u16x8 o;
        o[0] = f2bf(a.x); o[1] = f2bf(a.y); o[2] = f2bf(a.z); o[3] = f2bf(a.w);
        o[4] = f2bf(b.x); o[5] = f2bf(b.y); o[6] = f2bf(b.z); o[7] = f2bf(b.w);
        *(u16x8*)(wb + (size_t)t * 393216 + i) = o;
        return;
    }
    bid -= 576;                              // transpose: 84 x 4 x 4
    int xb = bid % 84;
    int c0 = ((bid / 84) & 3) * 64;
    int b  = bid / 336;
    const float* xp; int tb, HW, lvl_off;
    if (xb < 64)      { xp = x0; tb = xb;      HW = 4096; lvl_off = 0;      }
    else if (xb < 80) { xp = x1; tb = xb - 64; HW = 1024; lvl_off = OFF_L1; }
    else              { xp = x2; tb = xb - 80; HW = 256;  lvl_off = OFF_L2; }
    int hw0 = tb * 64;
    xp += (size_t)b * 256 * HW;
    int tx = threadIdx.x & 63;
    int ty = threadIdx.x >> 6;               // 0..3
#pragma unroll
    for (int i = 0; i < 16; ++i) {
        int c = c0 + ty * 16 + i;
        tile[ty * 16 + i][tx] = f2bf(xp[(size_t)c * HW + hw0 + tx]);
    }
    __syncthreads();
    unsigned short* op = xT + ((size_t)lvl_off + (size_t)b * HW + hw0) * 256 + c0;
#pragma unroll
    for (int i = 0; i < 16; ++i) {
        int r = ty * 16 + i;                 // local hw row
        op[(size_t)r * 256 + tx] = tile[tx][r];
    }
}

// ---------------- QKV GEMM: BK=64, 4 K-iters (half the barrier drains) ------
// Per buffer: A = 2 fragment-ordered 32-k halves (16KB), B same (16KB).
// 32 MFMA/wave between drains (vs 16 at BK=32). 64KB LDS -> 2 blocks/CU,
// 8 waves/CU (same TLP as the measured r12 config). XCD co-located grid.
__global__ __launch_bounds__(256, 2) void qkv_gemm_kernel(
    const unsigned short* __restrict__ wb,
    const float* __restrict__ bq, const float* __restrict__ bk,
    const float* __restrict__ bv,
    const unsigned short* __restrict__ xT,
    unsigned short* __restrict__ qkv)
{
    int bid  = blockIdx.x;                       // 2016 = 8 * 252
    int xcd  = bid & 7;
    int m    = xcd >> 1;
    int rest = bid >> 3;                         // 0..251
    int z    = rest / 84;                        // 0..2
    int ntl  = rest % 84;
    int nt   = (xcd & 1) * 84 + ntl;             // 0..167
    int bm0  = m * 128;
    int bn0  = nt * 128;
    int lvl = (bn0 >= OFF_L2) ? 2 : (bn0 >= OFF_L1) ? 1 : 0;
    const unsigned short* Wm = wb + ((size_t)z * 3 + lvl) * 131072;
    const float* bias = ((z == 0) ? bq : (z == 1) ? bk : bv) + lvl * 512;
    unsigned short* out = qkv + (size_t)z * 512 * NT_ALL;

    __shared__ unsigned short smem[2][16384];    // per buf: A 8192, B 8192

    int tid  = threadIdx.x;
    int lane = tid & 63;
    int wid  = tid >> 6;
    int wr   = wid >> 1, wc = wid & 1;
    int l15  = lane & 15;
    int kg   = lane >> 4;

    f32x4 acc[4][4];
#pragma unroll
    for (int i = 0; i < 4; ++i)
#pragma unroll
        for (int j = 0; j < 4; ++j) acc[i][j] = (f32x4){0.f, 0.f, 0.f, 0.f};

    int aRow0 = bm0 + (2 * wid)     * 16 + l15;
    int aRow1 = bm0 + (2 * wid + 1) * 16 + l15;
    int bRow0 = bn0 + (2 * wid)     * 16 + l15;
    int bRow1 = bn0 + (2 * wid + 1) * 16 + l15;
    int kbase = kg * 8;

    auto STAGE = [&](int t, int bufi) {          // stage 64-k tile (2 halves)
        int kk = t * 64 + kbase;
        unsigned short* As = smem[bufi];
        unsigned short* Bs = As + 8192;
#pragma unroll
        for (int hh = 0; hh < 2; ++hh) {
            int kkh = kk + hh * 32;
            int lo  = hh * 4096;
            async16(As + lo + (2 * wid)     * 512, Wm + (size_t)aRow0 * 256 + kkh);
            async16(As + lo + (2 * wid + 1) * 512, Wm + (size_t)aRow1 * 256 + kkh);
            async16(Bs + lo + (2 * wid)     * 512, xT + (size_t)bRow0 * 256 + kkh);
            async16(Bs + lo + (2 * wid + 1) * 512, xT + (size_t)bRow1 * 256 + kkh);
        }
    };

    STAGE(0, 0);
    __syncthreads();

    for (int it = 0; it < 4; ++it) {
        if (it < 3) STAGE(it + 1, (it + 1) & 1);
#pragma unroll
        for (int sub = 0; sub < 2; ++sub) {
            const unsigned short* As = smem[it & 1] + sub * 4096;
            const unsigned short* Bs = smem[it & 1] + 8192 + sub * 4096;
            bf16x8 af[4], bg[4];
#pragma unroll
            for (int mi = 0; mi < 4; ++mi)
                af[mi] = *reinterpret_cast<const bf16x8*>(As + ((wr * 4 + mi) * 64 + lane) * 8);
#pragma unroll
            for (int ni = 0; ni < 4; ++ni)
                bg[ni] = *reinterpret_cast<const bf16x8*>(Bs + ((wc * 4 + ni) * 64 + lane) * 8);
#pragma unroll
            for (int mi = 0; mi < 4; ++mi)
#pragma unroll
                for (int ni = 0; ni < 4; ++ni)
                    acc[mi][ni] = __builtin_amdgcn_mfma_f32_16x16x32_bf16(
                        af[mi], bg[ni], acc[mi][ni], 0, 0, 0);
        }
        __syncthreads();
    }

    // ---- epilogue: LDS transpose, 2 passes x 64 rows ----
    unsigned short* T = smem[0];                 // 64*136 = 8704 shorts, fits
#pragma unroll
    for (int p = 0; p < 2; ++p) {
        __syncthreads();
#pragma unroll
        for (int s = 0; s < 2; ++s) {
            int mi = 2 * p + s;
            int qw = wr * 32 + s * 16 + kg * 4;
            int ow = bm0 + wr * 64 + mi * 16 + kg * 4;
#pragma unroll
            for (int ni = 0; ni < 4; ++ni) {
                int cn = wc * 64 + ni * 16 + l15;
#pragma unroll
                for (int r = 0; r < 4; ++r)
                    T[(qw + r) * 136 + cn] = f2bf(acc[mi][ni][r] + bias[ow + r]);
            }
        }
        __syncthreads();
        int q  = tid >> 2;
        int j4 = tid & 3;
        int o  = bm0 + (q >> 5) * 64 + (2 * p + ((q >> 4) & 1)) * 16 + (q & 15);
        unsigned short* orow = out + (size_t)o * NT_ALL + bn0;
#pragma unroll
        for (int c = 0; c < 4; ++c) {
            int nl = c * 32 + j4 * 8;
            *(u16x8*)(orow + nl) = *(const u16x8*)(T + q * 136 + nl);
        }
    }
}

// ---------------- 3x3 local attention (r17/r18, unchanged) ------------------
__global__ __launch_bounds__(256, 4) void attn_kernel(
    const unsigned short* __restrict__ qkv,
    const float* __restrict__ bk, const float* __restrict__ bv,
    const float* __restrict__ relh, const float* __restrict__ relw,
    float* __restrict__ feat)
{
    int id  = blockIdx.x;                    // 0..3071
    int c   = (id & 7) * 64 + (id >> 3) / 6;
    int xb  = (id >> 3) % 6;
    int tid = threadIdx.x;
    int lvl, lgW, lvl_off, b, pair, w0, rwidth;
    bool active = true;
    if (xb < 4) {        // L0: one batch per xb
        lvl = 0; lgW = 6; lvl_off = 0;      b = xb;
        pair = tid >> 3; w0 = (tid & 7) * 8; rwidth = 64;
    } else if (xb == 4) { // L1: 4 batches x 64 threads
        lvl = 1; lgW = 5; lvl_off = OFF_L1; b = tid >> 6;
        pair = (tid & 63) >> 2; w0 = (tid & 3) * 8; rwidth = 64;
    } else {             // L2: 4 batches x 16 threads (tid<64)
        lvl = 2; lgW = 4; lvl_off = OFF_L2; b = (tid >> 4) & 3;
        pair = (tid & 15) >> 1; w0 = (tid & 1) * 8; rwidth = 16;
        active = tid < 64;
    }
    int W = 1 << lgW, H = W, HW = W << lgW;
    int h0 = 2 * pair;

    size_t n0 = (size_t)lvl_off + (size_t)b * HW + (h0 << lgW) + w0;
    const unsigned short* qp = qkv + (size_t)c          * NT_ALL + n0;
    const unsigned short* kp = qkv + ((size_t)512 + c)  * NT_ALL + n0;
    const unsigned short* vp = qkv + ((size_t)1024 + c) * NT_ALL + n0;

    float bkc = bk[lvl * 512 + c], bvc = bv[lvl * 512 + c];
    bool ish = (c < 256);
    const float* rsp = ish ? (relh + lvl * 768 + c * 3)
                           : (relw + lvl * 768 + (c - 256) * 3);
    float rs0 = rsp[0], rs1 = rsp[1], rs2 = rsp[2];

    float ysum = 0.f;
    if (active) {
        bool hasL = (w0 > 0), hasR = (w0 + 8 < W);
        float kf[4][10], vf[4][10];
#pragma unroll
        for (int r = 0; r < 4; ++r) {
            int y = h0 + r - 1;
            if ((unsigned)y < (unsigned)H) {
                int off = (r - 1) << lgW;
                u32x4 kv = *(const u32x4*)(kp + off);
                u32x4 vv = *(const u32x4*)(vp + off);
#pragma unroll
                for (int d = 0; d < 4; ++d) {
                    kf[r][1 + 2 * d] = lo16(kv[d]); kf[r][2 + 2 * d] = hi16(kv[d]);
                    vf[r][1 + 2 * d] = lo16(vv[d]); vf[r][2 + 2 * d] = hi16(vv[d]);
                }
                kf[r][0] = hasL ? hi16(*(const unsigned*)(kp + off - 2)) : bkc;
                vf[r][0] = hasL ? hi16(*(const unsigned*)(vp + off - 2)) : bvc;
                kf[r][9] = hasR ? lo16(*(const unsigned*)(kp + off + 8)) : bkc;
                vf[r][9] = hasR ? lo16(*(const unsigned*)(vp + off + 8)) : bvc;
            } else {
#pragma unroll
                for (int j = 0; j < 10; ++j) { kf[r][j] = bkc; vf[r][j] = bvc; }
            }
        }
#define ROW(rw, q0, q1, q2)                                        \
        {                                                          \
            float p0 = fexp2(fmaf(qln, kf[rw][j + 0], q0));        \
            float p1 = fexp2(fmaf(qln, kf[rw][j + 1], q1));        \
            float p2 = fexp2(fmaf(qln, kf[rw][j + 2], q2));        \
            num = fmaf(p0, vf[rw][j + 0], num);                    \
            num = fmaf(p1, vf[rw][j + 1], num);                    \
            num = fmaf(p2, vf[rw][j + 2], num);                    \
            den += p0 + p1 + p2;                                   \
        }
#pragma unroll
        for (int orow = 0; orow < 2; ++orow) {
            u32x4 qv = *(const u32x4*)(qp + (orow << lgW));
            float qf[8];
#pragma unroll
            for (int d = 0; d < 4; ++d) {
                qf[2 * d] = lo16(qv[d]); qf[2 * d + 1] = hi16(qv[d]);
            }
            if (ish) {
#pragma unroll
                for (int j = 0; j < 8; ++j) {
                    float qln = qf[j] * LOG2E;
                    float pr0 = qln * rs0, pr1 = qln * rs1, pr2 = qln * rs2;
                    float num = 0.f, den = 0.f;
                    ROW(orow + 0, pr0, pr0, pr0)
                    ROW(orow + 1, pr1, pr1, pr1)
                    ROW(orow + 2, pr2, pr2, pr2)
                    ysum += fmaxf(num * frcp(den), 0.f);
                }
            } else {
#pragma unroll
                for (int j = 0; j < 8; ++j) {
                    float qln = qf[j] * LOG2E;
                    float pr0 = qln * rs0, pr1 = qln * rs1, pr2 = qln * rs2;
                    float num = 0.f, den = 0.f;
                    ROW(orow + 0, pr0, pr1, pr2)
                    ROW(orow + 1, pr0, pr1, pr2)
                    ROW(orow + 2, pr0, pr1, pr2)
                    ysum += fmaxf(num * frcp(den), 0.f);
                }
            }
        }
#undef ROW
        ysum *= (1.0f / HW);
    }
    if (rwidth == 64) {
#pragma unroll
        for (int off = 32; off; off >>= 1) ysum += __shfl_down(ysum, off, 64);
        if (active && ((tid & 63) == 0))
            atomicAdd(&feat[(size_t)b * 512 + c], ysum);
    } else {
#pragma unroll
        for (int off = 8; off; off >>= 1) ysum += __shfl_down(ysum, off, 16);
        if (active && ((tid & 15) == 0))
            atomicAdd(&feat[(size_t)b * 512 + c], ysum);
    }
}

// ---------------- classifiers: grid-stride, feat held in registers ---------
__global__ __launch_bounds__(256, 4) void logits_kernel(
    const float* __restrict__ feat,
    const float* __restrict__ ws, const float* __restrict__ bs,
    const float* __restrict__ wf, const float* __restrict__ bff,
    const float* __restrict__ wo, const float* __restrict__ bo,
    float* __restrict__ out)
{
    int lane = threadIdx.x & 63;
    int wid  = threadIdx.x >> 6;
    f32x4 fr[4][2];
#pragma unroll
    for (int b = 0; b < 4; ++b) {
        fr[b][0] = *(const f32x4*)(feat + b * 512 + lane * 4);
        fr[b][1] = *(const f32x4*)(feat + b * 512 + 256 + lane * 4);
    }
    const int ROWS = 64500 + 489 + 140;
    for (int row = blockIdx.x * 4 + wid; row < ROWS; row += 8192) {
        const float* wm; float bias; size_t obase; int ostride;
        if (row < 64500) {
            wm = ws + (size_t)row * 512; bias = bs[row]; obase = (size_t)row; ostride = 64500;
        } else if (row < 64500 + 489) {
            int r = row - 64500;
            wm = wf + (size_t)r * 512; bias = bff[r]; obase = 258000 + (size_t)r; ostride = 489;
        } else {
            int r = row - 64989;
            wm = wo + (size_t)r * 512; bias = bo[r]; obase = 259956 + (size_t)r; ostride = 140;
        }
        f32x4 w1 = *(const f32x4*)(wm + lane * 4);
        f32x4 w2 = *(const f32x4*)(wm + 256 + lane * 4);
        float accs[4];
#pragma unroll
        for (int b = 0; b < 4; ++b) {
            f32x4 f1 = fr[b][0], f2 = fr[b][1];
            accs[b] = w1.x * f1.x + w1.y * f1.y + w1.z * f1.z + w1.w * f1.w
                    + w2.x * f2.x + w2.y * f2.y + w2.z * f2.z + w2.w * f2.w;
        }
#pragma unroll
        for (int off = 32; off; off >>= 1)
#pragma unroll
            for (int b = 0; b < 4; ++b) accs[b] += __shfl_down(accs[b], off, 64);
        if (lane == 0)
#pragma unroll
            for (int b = 0; b < 4; ++b) out[obase + (size_t)b * ostride] = accs[b] + bias;
    }
}

extern "C" void kernel_launch(void* const* d_in, const int* in_sizes, int n_in,
                              void* d_out, int out_size, void* d_ws, size_t ws_size,
                              hipStream_t stream)
{
    const float* x0  = (const float*)d_in[0];
    const float* x1  = (const float*)d_in[1];
    const float* x2  = (const float*)d_in[2];
    const float* wq  = (const float*)d_in[3];
    const float* bq  = (const float*)d_in[4];
    const float* wk  = (const float*)d_in[5];
    const float* bk  = (const float*)d_in[6];
    const float* wv  = (const float*)d_in[7];
    const float* bv  = (const float*)d_in[8];
    const float* relh = (const float*)d_in[9];
    const float* relw = (const float*)d_in[10];
    const float* ws  = (const float*)d_in[11];
    const float* bs  = (const float*)d_in[12];
    const float* wf  = (const float*)d_in[13];
    const float* bff = (const float*)d_in[14];
    const float* wo  = (const float*)d_in[15];
    const float* bo  = (const float*)d_in[16];
    float* out = (float*)d_out;

    char* wsb = (char*)d_ws;
    float* feat = (float*)wsb;                                   // 8 KB
    unsigned short* wb = (unsigned short*)(wsb + 8192);          // 2.36 MB
    unsigned short* xT = (unsigned short*)(wsb + 8192 + 2359296);          // 11 MB
    unsigned short* qkv = (unsigned short*)(wsb + 8192 + 2359296 + 11010048); // 66 MB

    prep_kernel<<<dim3(1 + 576 + 1344), 256, 0, stream>>>(
        x0, x1, x2, wq, wk, wv, wb, xT, feat);
    qkv_gemm_kernel<<<dim3(2016), 256, 0, stream>>>(
        wb, bq, bk, bv, xT, qkv);
    attn_kernel<<<dim3(3072), 256, 0, stream>>>(
        qkv, bk, bv, relh, relw, feat);
    logits_kernel<<<dim3(2048), 256, 0, stream>>>(feat, ws, bs, wf, bff, wo, bo, out);
}